// Round 10
// baseline (161.521 us; speedup 1.0000x reference)
//
#include <hip/hip_runtime.h>
#include <math.h>

// Capsule routing, u_hat never materialized (factors through W):
//   v[b,n,c] = sum_i c[b,n,i] u[b,i,c]
//   s[b,n,d] = sum_c v[b,n,c] W[c,n*64+d];  o = squash(s)
//   t[b,n,c] = sum_d o[b,n,d] W[c,n*64+d]
//   b[b,n,i] = sum_c t[b,n,c] u[b,i,c]
// Iter 0: b=0 -> c uniform 1/32 -> v0 = colsum(u)/32.
//
// R10: consolidation. Measured floor analysis: R7-R9 each removed real work
// but moved the total only 2-5 us => ~110 us of the 159 is harness overhead
// (268 MB ws poison fill = 43-45 us + restores + graph replay), my 6-kernel
// chain is ~50 us. This round: sst emits t as bf16 (same RNE pack route did),
// so route loses its whole t-staging loop + 1 barrier (phase A B-frags load
// 16 B/lane straight from L2-hot global); softmax packs cm_l bf16 in place
// (another barrier + 2K ops gone). Numerically bit-identical to R9.
// grid.sync stays banned (R4: ~1000us spin, 516 MB WRITE).

constexpr int Bn = 32, In = 1024, Cn = 256, Nn = 32, Dn = 64, ND = 2048;

typedef __attribute__((ext_vector_type(8))) short bf16x8;
typedef __attribute__((ext_vector_type(4))) float f32x4;

__device__ __forceinline__ unsigned int packbf2(float a, float b) {
  unsigned int xa = __float_as_uint(a), xb = __float_as_uint(b);
  xa = (xa + 0x7fffu + ((xa >> 16) & 1u)) >> 16;  // RNE
  xb = (xb + 0x7fffu + ((xb >> 16) & 1u)) >> 16;
  return xa | (xb << 16);
}
__device__ __forceinline__ unsigned short packbf1(float a) {
  unsigned int x = __float_as_uint(a);
  return (unsigned short)((x + 0x7fffu + ((x >> 16) & 1u)) >> 16);
}
__device__ __forceinline__ float bfu(unsigned short us) {
  return __uint_as_float((unsigned int)us << 16);
}

// ---- k_pre: colsum (z<1024) | WbfT transpose (1024..1151) | Wbf cast -------
__global__ __launch_bounds__(256) void k_pre(
    const float* __restrict__ u, const float* __restrict__ W,
    float* __restrict__ psu, unsigned short* __restrict__ Wbf,
    unsigned short* __restrict__ WbfT) {
  const int z = blockIdx.x, tid = threadIdx.x;
  if (z < 1024) {  // colsum: psu[z*256+c] = sum over 32 i of u[b, ch*32+i, c]
    int b = z >> 5, ch = z & 31;
    const float* up = u + ((size_t)(b * In + ch * 32)) * Cn + tid;
    float s = 0.f;
#pragma unroll 8
    for (int j = 0; j < 32; ++j) s += up[(size_t)j * Cn];
    psu[(size_t)z * Cn + tid] = s;
  } else if (z < 1152) {  // WbfT[nd][c] = bf16(W[c][nd]), 64x64 tiles
    __shared__ float tile[64][65];
    int t = z - 1024;
    int x0 = (t & 31) * 64, y0 = (t >> 5) * 64;  // x=nd, y=c
    int lx = tid & 63, ly = tid >> 6;
#pragma unroll
    for (int k = 0; k < 16; ++k) {
      int y = ly + k * 4;
      tile[y][lx] = W[(size_t)(y0 + y) * ND + x0 + lx];
    }
    __syncthreads();
#pragma unroll
    for (int k = 0; k < 8; ++k) {  // 64 rows x 32 uints
      int idx = tid + k * 256;
      int row = idx >> 5, cu = idx & 31;
      unsigned int v = packbf2(tile[2 * cu][row], tile[2 * cu + 1][row]);
      *(unsigned int*)&WbfT[(size_t)(x0 + row) * Cn + y0 + 2 * cu] = v;
    }
  } else {  // Wbf: straight cast, 128 blocks x 4096 floats
    int zb = z - 1152;
    const float* src = W + (size_t)zb * 4096;
    unsigned short* dst = Wbf + (size_t)zb * 4096;
#pragma unroll
    for (int k = 0; k < 4; ++k) {
      int off = k * 1024 + tid * 4;
      const float4 v = *(const float4*)&src[off];
      *(uint2*)&dst[off] = make_uint2(packbf2(v.x, v.y), packbf2(v.z, v.w));
    }
  }
}

// ---- fused: v-reduce -> s -> squash -> [out] -> [t bf16] -------------------
__global__ __launch_bounds__(256) void k_sst(
    const void* __restrict__ src, int srcBf16, int count, long bS, long nS,
    long cS, float scale, const unsigned short* __restrict__ Wbf,
    const unsigned short* __restrict__ WbfT, unsigned short* __restrict__ tbb,
    float* __restrict__ outp, int writeT) {
  int bn = blockIdx.x, b = bn >> 5, n = bn & 31;
  int tid = threadIdx.x;
  __shared__ float vs[Cn];
  __shared__ float red[Cn];
  __shared__ float ol[Dn];
  {  // v-reduce (lanes = c, coalesced)
    float s = 0.f;
    if (srcBf16) {
      const unsigned short* p = (const unsigned short*)src + b * bS + n * nS + tid;
      for (int ch = 0; ch < count; ++ch) s += bfu(p[(size_t)ch * cS]);
    } else {
      const float* p = (const float*)src + b * bS + n * nS + tid;
      for (int ch = 0; ch < count; ++ch) s += p[(size_t)ch * cS];
    }
    vs[tid] = s * scale;
  }
  __syncthreads();
  {  // s partials: thread (q = tid>>6, d = tid&63); Wbf rows 128 B coalesced
    int q = tid >> 6, d = tid & 63;
    const unsigned short* wp = Wbf + (size_t)(q * 64) * ND + (size_t)n * Dn + d;
    float a = 0.f;
#pragma unroll 8
    for (int c2 = 0; c2 < 64; ++c2) a += vs[q * 64 + c2] * bfu(wp[(size_t)c2 * ND]);
    red[tid] = a;
  }
  __syncthreads();
  if (tid < 64) {  // squash (one full wave)
    float a = red[tid] + red[64 + tid] + red[128 + tid] + red[192 + tid];
    float sq = a * a;
#pragma unroll
    for (int off = 32; off > 0; off >>= 1) sq += __shfl_xor(sq, off, 64);
    float o = a / sqrtf(sq + 1e-7f);
    ol[tid] = o;
    if (outp) outp[(size_t)bn * Dn + tid] = o;
  }
  __syncthreads();
  if (writeT) {  // t[c] = sum_d ol[d] * WbfT[n*64+d][c]; pack bf16 for route
    const unsigned short* wt = WbfT + (size_t)(n * Dn) * Cn + tid;
    float a = 0.f;
#pragma unroll 8
    for (int d2 = 0; d2 < 64; ++d2) a += ol[d2] * bfu(wt[(size_t)d2 * Cn]);
    tbb[(size_t)bn * Cn + tid] = packbf1(a);
  }
}

// ---- fused routing step (MFMA): bb = u.t^T -> softmax -> pv = c.u ----------
// Block (b, it): i-tile of 32, 256 threads (4 waves). t read from global bf16.
__global__ __launch_bounds__(256, 4) void k_route(
    const unsigned short* __restrict__ tbb, const float* __restrict__ u,
    unsigned short* __restrict__ pvb) {
  const int b = blockIdx.x, itile = blockIdx.y, i0 = itile * 32;
  const int tid = threadIdx.x;
  const int lane = tid & 63, w = tid >> 6;
  const int mrow = lane & 15, quad = lane >> 4;

  __shared__ unsigned short u_t[256][40];   // bf16 i-major; row 80 B
  __shared__ unsigned short cm_l[32][40];   // bf16 softmax(c)
  __shared__ float bb_l[32][36];

  // ---- stage u_t only (lane-transposed reads, conflict-free writes) ----
  {
    const int ti = tid & 31, qb = tid >> 5;
    const float* up = u + ((size_t)(b * In + i0 + ti)) * Cn;
#pragma unroll
    for (int m = 0; m < 8; ++m) {
      int q = qb + m * 8;
      const float4 uv = *(const float4*)&up[q * 4];
      u_t[q * 4 + 0][ti] = packbf1(uv.x);
      u_t[q * 4 + 1][ti] = packbf1(uv.y);
      u_t[q * 4 + 2][ti] = packbf1(uv.z);
      u_t[q * 4 + 3][ti] = packbf1(uv.w);
    }
  }
  __syncthreads();

  // ---- phase A: D[i,n] = sum_c u[i,c] t[n,c]; B-frag from global (L2-hot) --
  {
    const int i0t = (w & 1) * 16, n0t = (w >> 1) * 16;
    const float* ub = u + ((size_t)(b * In + i0 + i0t + mrow)) * Cn + quad * 8;
    const unsigned short* tr =
        tbb + ((size_t)(b * Nn + n0t + mrow)) * Cn + quad * 8;
    f32x4 acc = {0.f, 0.f, 0.f, 0.f};
#pragma unroll
    for (int k0 = 0; k0 < 8; ++k0) {       // c = k0*32 + quad*8 + j
      const float4 a0 = *(const float4*)(ub + k0 * 32);
      const float4 a1 = *(const float4*)(ub + k0 * 32 + 4);
      union { unsigned int ui[4]; bf16x8 v; } af;
      af.ui[0] = packbf2(a0.x, a0.y); af.ui[1] = packbf2(a0.z, a0.w);
      af.ui[2] = packbf2(a1.x, a1.y); af.ui[3] = packbf2(a1.z, a1.w);
      const bf16x8 bf = *(const bf16x8*)(tr + k0 * 32);
      acc = __builtin_amdgcn_mfma_f32_16x16x32_bf16(af.v, bf, acc, 0, 0, 0);
    }
    // D: col=lane&15 -> n within tile, row=quad*4+reg -> i within tile
#pragma unroll
    for (int r = 0; r < 4; ++r)
      bb_l[n0t + mrow][i0t + quad * 4 + r] = acc[r];
  }
  __syncthreads();

  // ---- softmax over n per i; write bf16 c directly (merged pack) ----
  if (tid < 32) {
    float m = -1e30f;
#pragma unroll
    for (int n = 0; n < Nn; ++n) m = fmaxf(m, bb_l[n][tid]);
    float e[Nn];
    float ssum = 0.f;
#pragma unroll
    for (int n = 0; n < Nn; ++n) { e[n] = __expf(bb_l[n][tid] - m); ssum += e[n]; }
    float inv = 1.f / ssum;
#pragma unroll
    for (int n = 0; n < Nn; ++n) cm_l[n][tid] = packbf1(e[n] * inv);
  }
  __syncthreads();

  // ---- phase B: D[n,c] = sum_i c[n,i] u[i,c]; K=32 -> 1 MFMA/tile ----
  {
    const int mt = w & 1;                  // ncap tile (0..1)
    const bf16x8 af = *(const bf16x8*)&cm_l[mt * 16 + mrow][quad * 8];
#pragma unroll
    for (int j = 0; j < 8; ++j) {
      const int ct = (w >> 1) * 8 + j;     // c tile (0..15)
      const bf16x8 bf = *(const bf16x8*)&u_t[ct * 16 + mrow][quad * 8];
      f32x4 d = {0.f, 0.f, 0.f, 0.f};
      d = __builtin_amdgcn_mfma_f32_16x16x32_bf16(af, bf, d, 0, 0, 0);
      // D: col=lane&15 -> c within tile, row=quad*4+reg -> ncap within tile
#pragma unroll
      for (int r = 0; r < 4; ++r)
        pvb[((size_t)((b * 32 + itile) * Nn + mt * 16 + quad * 4 + r)) * Cn +
            ct * 16 + mrow] = packbf1(d[r]);
    }
  }
}

extern "C" void kernel_launch(void* const* d_in, const int* in_sizes, int n_in,
                              void* d_out, int out_size, void* d_ws, size_t ws_size,
                              hipStream_t stream) {
  (void)in_sizes; (void)n_in; (void)out_size; (void)ws_size;
  const float* u = (const float*)d_in[0];   // (32,1024,256)
  const float* W = (const float*)d_in[1];   // (256,2048)
  float* out = (float*)d_out;               // (32,32,64)
  float* ws = (float*)d_ws;
  // ws layout (float units): pvb bf16 8388608 ush = 4194304 | psu 262144 |
  // Wbf 524288 ush = 262144 | WbfT 262144 | tbb 32768 ush = 16384  => 20 MB.
  unsigned short* pvb  = (unsigned short*)ws;
  float*          psu  = ws + 4194304;
  unsigned short* Wbf  = (unsigned short*)(ws + 4456448);
  unsigned short* WbfT = (unsigned short*)(ws + 4718592);
  unsigned short* tbb  = (unsigned short*)(ws + 4980736);

  k_pre<<<1280, 256, 0, stream>>>(u, W, psu, Wbf, WbfT);
  // iter 0: v0 = colsum/32 (psu fp32: b-stride 8192, ch-stride 256)
  k_sst<<<1024, 256, 0, stream>>>(psu, 0, 32, 8192L, 0L, 256L, 1.0f / 32.0f,
                                  Wbf, WbfT, tbb, nullptr, 1);
  // iter 1
  k_route<<<dim3(32, 32), 256, 0, stream>>>(tbb, u, pvb);
  // pvb bf16: b-stride 262144, n-stride 256, it-stride 8192 (ushort units)
  k_sst<<<1024, 256, 0, stream>>>(pvb, 1, 32, 262144L, 256L, 8192L, 1.0f,
                                  Wbf, WbfT, tbb, nullptr, 1);
  // iter 2 (final)
  k_route<<<dim3(32, 32), 256, 0, stream>>>(tbb, u, pvb);
  k_sst<<<1024, 256, 0, stream>>>(pvb, 1, 32, 262144L, 256L, 8192L, 1.0f,
                                  Wbf, WbfT, tbb, out, 0);
}